// Round 6
// baseline (36.306 us; speedup 1.0000x reference)
//
#include <hip/hip_runtime.h>
#include <math.h>

// Problem constants (match reference)
#define Bq 4
#define Nq 80
#define CHq 64
#define GAMMAq 4.0f
#define EPSq 1e-6f
#define PCWL 100     // LDS row pad (avoid 32-bank stride)
#define NQUAD 24     // float4 quads per (na,u): 96 floats

// Packed comp map (per (na,u), 96 floats, stored as quads interleaved by u):
//   0-2   A00[k]        3-5   A10[k]       6-14  C01[k][j]
//   15-23 P0[k][j]      24-32 P1[k][j]     33-41 P2[k][j]
//   42 r1s  43-45 r1v   46-47 pad
//   48+c (c=0..41): wr2-mixed copies of comps 0..41 (r2 fold)   90-95 pad
// Global layout: pc_quad[ na ][ c4 0..23 ][ u 0..15 ]  (float4 each)
//   -> 16 u-lanes read 256B contiguous per quad: fully coalesced.

// ---------------------------------------------------------------------------
// Kernel 1: 80 blocks x 256 threads; each WAVE handles one na (4 na/block).
// ---------------------------------------------------------------------------
__global__ __launch_bounds__(256) void se3_precomp(
    const float* __restrict__ h_nei,   // [B][CH][N]
    const float* __restrict__ x,       // [B][CH][N]
    const float* __restrict__ w00,     // [M][M][3]
    const float* __restrict__ w10,
    const float* __restrict__ w01,
    const float* __restrict__ w11,     // [3][M][M][3]
    const float* __restrict__ wr10,    // [M][M]
    const float* __restrict__ wr11,
    const float* __restrict__ wr20,    // [M][M]
    const float* __restrict__ wr21,
    float* __restrict__ pc)
{
    const int wv = threadIdx.x >> 6;           // wave 0..3
    const int na = blockIdx.x * 4 + wv;        // 0..319
    const int n  = na / Nq, a = na - n * Nq;
    const int tt = threadIdx.x & 63;
    const int u  = tt & 15;
    const int kk = tt >> 4;                    // 0..3

    __shared__ float hsh[4][64];
    __shared__ float xsh[4][64];
    __shared__ float pout[4][16][PCWL];        // 25.6 KB

    hsh[wv][tt] = h_nei[(size_t)n * CHq * Nq + tt * Nq + a];
    xsh[wv][tt] = x    [(size_t)n * CHq * Nq + tt * Nq + a];
    __syncthreads();

    if (kk < 3) {
        const int k = kk;
        float a00 = 0.f, a10 = 0.f;
        float c[3] = {0.f,0.f,0.f}, p0[3] = {0.f,0.f,0.f};
        float p1[3] = {0.f,0.f,0.f}, p2[3] = {0.f,0.f,0.f};
#pragma unroll
        for (int v = 0; v < 16; ++v) {
            const float s = hsh[wv][v];
            a00 += w00[(u * 16 + v) * 3 + k] * s;
            a10 += w10[(u * 16 + v) * 3 + k] * s;
            const float w01v = w01[(u * 16 + v) * 3 + k];
            const float w110 = w11[((0 * 16 + u) * 16 + v) * 3 + k];
            const float w111 = w11[((1 * 16 + u) * 16 + v) * 3 + k];
            const float w112 = w11[((2 * 16 + u) * 16 + v) * 3 + k];
#pragma unroll
            for (int j = 0; j < 3; ++j) {
                const float Vj = hsh[wv][16 + v * 3 + j];
                c[j]  += w01v * Vj;
                p0[j] += w110 * Vj;
                p1[j] += w111 * Vj;
                p2[j] += w112 * Vj;
            }
        }
        pout[wv][u][0 + k] = a00;
        pout[wv][u][3 + k] = a10;
#pragma unroll
        for (int j = 0; j < 3; ++j) {
            pout[wv][u][6  + k * 3 + j] = c[j];
            pout[wv][u][15 + k * 3 + j] = p0[j];
            pout[wv][u][24 + k * 3 + j] = p1[j];
            pout[wv][u][33 + k * 3 + j] = p2[j];
        }
    } else {
        // r1 = SI(x) for this u
        float r1s = 0.f, r1v[3] = {0.f, 0.f, 0.f};
#pragma unroll
        for (int v = 0; v < 16; ++v) {
            r1s += wr10[u * 16 + v] * xsh[wv][v];
            const float wvv = wr11[u * 16 + v];
#pragma unroll
            for (int j = 0; j < 3; ++j) r1v[j] += wvv * xsh[wv][16 + v * 3 + j];
        }
        pout[wv][u][42] = r1s;
#pragma unroll
        for (int j = 0; j < 3; ++j) pout[wv][u][43 + j] = r1v[j];
        pout[wv][u][46] = 0.f; pout[wv][u][47] = 0.f;
#pragma unroll
        for (int j = 90; j < 96; ++j) pout[wv][u][j] = 0.f;
    }
    __syncthreads();

    // r2 fold: B[u][c] = sum_v wr2[u][v] * A[v][c]   (c = kk, kk+4, ..., <42)
    for (int c = kk; c < 42; c += 4) {
        const bool scalarType = (c < 3) || (c >= 6 && c < 15);
        const float* W = scalarType ? wr20 : wr21;
        float acc = 0.f;
#pragma unroll
        for (int v = 0; v < 16; ++v) acc += W[u * 16 + v] * pout[wv][v][c];
        pout[wv][u][48 + c] = acc;
    }
    __syncthreads();

    // interleaved quad write. thread (u,kk) writes quads kk, kk+4, ...
    {
        float4* dst = reinterpret_cast<float4*>(pc) + (size_t)na * (NQUAD * 16) + u;
#pragma unroll
        for (int i = 0; i < 6; ++i) {
            const int c4 = kk + i * 4;
            dst[c4 * 16] = make_float4(pout[wv][u][c4 * 4 + 0], pout[wv][u][c4 * 4 + 1],
                                       pout[wv][u][c4 * 4 + 2], pout[wv][u][c4 * 4 + 3]);
        }
    }
}

// ---------------------------------------------------------------------------
// Per-pair contraction: from the thread's pc row (pa/pb) and one b's geometry,
// produce h_conv (hcs,hv*) and gate-weighted (gcs,gv*) increments.
// ---------------------------------------------------------------------------
__device__ __forceinline__ void pair_contract(
    const float* __restrict__ pa, const float* __restrict__ pb,
    float d0, float d1, float d2, float m,
    float& ohcs, float& ohv0, float& ohv1, float& ohv2,
    float& ogcs, float& ogv0, float& ogv1, float& ogv2)
{
    const float rad = sqrtf(d0 * d0 + d1 * d1 + d2 * d2 + EPSq);
    const float inv = 1.0f / rad;
    const float nh0 = d0 * inv, nh1 = d1 * inv, nh2 = d2 * inv;
    float rb[3];
    rb[0] = __expf(-GAMMAq * rad * rad);
    { float t1 = rad - 0.5f; rb[1] = __expf(-GAMMAq * t1 * t1); }
    { float t2 = rad - 1.0f; rb[2] = __expf(-GAMMAq * t2 * t2); }

    float as_ = 0.f, a10 = 0.f;
    float c01[3] = {0.f,0.f,0.f}, p0[3] = {0.f,0.f,0.f};
    float p1[3] = {0.f,0.f,0.f}, p2[3] = {0.f,0.f,0.f};
    float bs_ = 0.f, b10 = 0.f;
    float bc01[3] = {0.f,0.f,0.f}, bp0[3] = {0.f,0.f,0.f};
    float bp1[3] = {0.f,0.f,0.f}, bp2[3] = {0.f,0.f,0.f};
#pragma unroll
    for (int k = 0; k < 3; ++k) {
        const float r = rb[k];
        as_ += r * pa[0 + k];
        a10 += r * pa[3 + k];
        bs_ += r * pb[0 + k];
        b10 += r * pb[3 + k];
#pragma unroll
        for (int j = 0; j < 3; ++j) {
            c01[j]  += r * pa[6  + k * 3 + j];
            p0[j]   += r * pa[15 + k * 3 + j];
            p1[j]   += r * pa[24 + k * 3 + j];
            p2[j]   += r * pa[33 + k * 3 + j];
            bc01[j] += r * pb[6  + k * 3 + j];
            bp0[j]  += r * pb[15 + k * 3 + j];
            bp1[j]  += r * pb[24 + k * 3 + j];
            bp2[j]  += r * pb[33 + k * 3 + j];
        }
    }
    const float third = 1.0f / 3.0f;

    const float hcs = m * (as_ + c01[0] * nh0 + c01[1] * nh1 + c01[2] * nh2);
    const float cr0 = p1[1] * nh2 - p1[2] * nh1;
    const float cr1 = p1[2] * nh0 - p1[0] * nh2;
    const float cr2 = p1[0] * nh1 - p1[1] * nh0;
    const float pd  = p2[0] * nh0 + p2[1] * nh1 + p2[2] * nh2;
    const float hv0 = m * (nh0 * a10 + p0[0] + cr0 + nh0 * pd - p2[0] * third);
    const float hv1 = m * (nh1 * a10 + p0[1] + cr1 + nh1 * pd - p2[1] * third);
    const float hv2 = m * (nh2 * a10 + p0[2] + cr2 + nh2 * pd - p2[2] * third);

    const float r2s = m * (bs_ + bc01[0] * nh0 + bc01[1] * nh1 + bc01[2] * nh2);
    const float br0 = bp1[1] * nh2 - bp1[2] * nh1;
    const float br1 = bp1[2] * nh0 - bp1[0] * nh2;
    const float br2 = bp1[0] * nh1 - bp1[1] * nh0;
    const float bpd = bp2[0] * nh0 + bp2[1] * nh1 + bp2[2] * nh2;
    const float r2v0 = m * (nh0 * b10 + bp0[0] + br0 + nh0 * bpd - bp2[0] * third);
    const float r2v1 = m * (nh1 * b10 + bp0[1] + br1 + nh1 * bpd - bp2[1] * third);
    const float r2v2 = m * (nh2 * b10 + bp0[2] + br2 + nh2 * bpd - bp2[2] * third);

    const float r1s  = pa[42];
    const float r1v0 = pa[43], r1v1 = pa[44], r1v2 = pa[45];

    const float rs  = 1.0f / (1.0f + __expf(-(r1s + r2s)));
    const float wv0 = r1v0 + r2v0, wv1 = r1v1 + r2v1, wv2 = r1v2 + r2v2;
    const float nn  = sqrtf(wv0 * wv0 + wv1 * wv1 + wv2 * wv2 + EPSq);
    const float sc  = (1.0f / (1.0f + __expf(-nn))) / nn;
    const float rv0 = wv0 * sc, rv1 = wv1 * sc, rv2 = wv2 * sc;
    const float fs  = fabsf(rs);
    const float fv  = sqrtf(rv0 * rv0 + rv1 * rv1 + rv2 * rv2 + EPSq);

    ohcs += hcs;      ohv0 += hv0;      ohv1 += hv1;      ohv2 += hv2;
    ogcs += fs * hcs; ogv0 += fv * hv0; ogv1 += fv * hv1; ogv2 += fv * hv2;
}

// ---------------------------------------------------------------------------
// Kernel 2: block per (n, b-pair) (160 blocks, 256 threads = 16 a-groups x 16 u).
// Each thread loads its pc row ONCE per a and contracts it for BOTH b's.
// ---------------------------------------------------------------------------
__global__ __launch_bounds__(256) void se3_main(
    const float* __restrict__ x,       // [B][CH][N]
    const float* __restrict__ hdiff,   // [B][N][N][3]
    const float* __restrict__ mask,    // [B][N][N]
    const float* __restrict__ wz0,     // [M][2M]
    const float* __restrict__ wz1,
    const float* __restrict__ wp0,
    const float* __restrict__ wp1,
    const float* __restrict__ pc,
    float* __restrict__ out)           // [B][CH][N]
{
    const int nb  = blockIdx.x;        // 0..159
    const int n   = nb / (Nq / 2);
    const int bp  = nb - n * (Nq / 2); // 0..39
    const int b0  = bp * 2;
    const int tid = threadIdx.x;
    const int g   = tid >> 4;          // a-group 0..15
    const int u   = tid & 15;          // channel 0..15

    __shared__ float wsh[4][512];      // wz0, wz1, wp0, wp1
    __shared__ float redW[4][16][16];
    __shared__ float sumHs[2][64], sumGs[2][64];

#pragma unroll
    for (int i = 0; i < 2; ++i) {
        const int idx = tid + i * 256;
        wsh[0][idx] = wz0[idx];
        wsh[1][idx] = wz1[idx];
        wsh[2][idx] = wp0[idx];
        wsh[3][idx] = wp1[idx];
    }

    float s0[8] = {0.f,0.f,0.f,0.f,0.f,0.f,0.f,0.f};  // b0: shs,shv0..2,sgs,sgv0..2
    float s1[8] = {0.f,0.f,0.f,0.f,0.f,0.f,0.f,0.f};  // b1

    const float* drow0 = hdiff + (size_t)(n * Nq + b0)     * Nq * 3;
    const float* drow1 = hdiff + (size_t)(n * Nq + b0 + 1) * Nq * 3;
    const float* mrow0 = mask  + (size_t)(n * Nq + b0)     * Nq;
    const float* mrow1 = mask  + (size_t)(n * Nq + b0 + 1) * Nq;

    for (int it = 0; it < 5; ++it) {
        const int a = it * 16 + g;

        // quad-interleaved, u-coalesced pc row read (once; serves both b's)
        const float4* p4 = reinterpret_cast<const float4*>(pc)
                         + (size_t)(n * Nq + a) * (NQUAD * 16) + u;
        float pa[48];
#pragma unroll
        for (int i = 0; i < 12; ++i)
            *reinterpret_cast<float4*>(&pa[i * 4]) = p4[i * 16];
        float pb[44];
#pragma unroll
        for (int i = 0; i < 11; ++i)
            *reinterpret_cast<float4*>(&pb[i * 4]) = p4[(12 + i) * 16];

        pair_contract(pa, pb, drow0[a*3+0], drow0[a*3+1], drow0[a*3+2], mrow0[a],
                      s0[0], s0[1], s0[2], s0[3], s0[4], s0[5], s0[6], s0[7]);
        pair_contract(pa, pb, drow1[a*3+0], drow1[a*3+1], drow1[a*3+2], mrow1[a],
                      s1[0], s1[1], s1[2], s1[3], s1[4], s1[5], s1[6], s1[7]);
    }

    // -------- reduce over 16 a-groups: shuffle within wave, LDS across waves
    float vals[16];
#pragma unroll
    for (int q = 0; q < 8; ++q) { vals[q] = s0[q]; vals[8 + q] = s1[q]; }
#pragma unroll
    for (int q = 0; q < 16; ++q) {
        vals[q] += __shfl_xor(vals[q], 16, 64);
        vals[q] += __shfl_xor(vals[q], 32, 64);
    }
    const int wave = tid >> 6;
    if ((tid & 63) < 16) {
#pragma unroll
        for (int q = 0; q < 16; ++q) redW[wave][q][u] = vals[q];
    }
    __syncthreads();

    if (tid < 16) {
        float tacc[16];
#pragma unroll
        for (int q = 0; q < 16; ++q)
            tacc[q] = redW[0][q][tid] + redW[1][q][tid] + redW[2][q][tid] + redW[3][q][tid];
#pragma unroll
        for (int b = 0; b < 2; ++b) {
            sumHs[b][tid] = tacc[b * 8 + 0];
            sumGs[b][tid] = tacc[b * 8 + 4];
#pragma unroll
            for (int j = 0; j < 3; ++j) {
                sumHs[b][16 + tid * 3 + j] = tacc[b * 8 + 1 + j];
                sumGs[b][16 + tid * 3 + j] = tacc[b * 8 + 5 + j];
            }
        }
    }
    __syncthreads();

    // -------- epilogue: z, pre_h, new_h (32 threads: lanes 0-15 b0, 16-31 b1)
    if (tid < 32) {
        const int bsel  = tid >> 4;
        const int u15   = tid & 15;
        const int bnode = b0 + bsel;
        const float* xb = x + (size_t)n * CHq * Nq + bnode;
        const float* SH = sumHs[bsel];
        const float* SG = sumGs[bsel];

        float zs_in = 0.f, ps_in = 0.f;
        float zv[3] = {0.f, 0.f, 0.f};
        float pv[3] = {0.f, 0.f, 0.f};
#pragma unroll
        for (int mm = 0; mm < 32; ++mm) {
            float Sh, Sg;
            if (mm < 16) { const float xv = xb[mm * Nq]; Sh = xv; Sg = xv; }
            else         { Sh = SH[mm - 16]; Sg = SG[mm - 16]; }
            zs_in += wsh[0][u15 * 32 + mm] * Sh;
            ps_in += wsh[2][u15 * 32 + mm] * Sg;
            const float wz = wsh[1][u15 * 32 + mm];
            const float wp = wsh[3][u15 * 32 + mm];
#pragma unroll
            for (int j = 0; j < 3; ++j) {
                float Vh, Vg;
                if (mm < 16) { const float xv = xb[(16 + mm * 3 + j) * Nq]; Vh = xv; Vg = xv; }
                else { Vh = SH[16 + (mm - 16) * 3 + j]; Vg = SG[16 + (mm - 16) * 3 + j]; }
                zv[j] += wz * Vh;
                pv[j] += wp * Vg;
            }
        }

        const float zs  = 1.0f / (1.0f + __expf(-zs_in));
        const float zn  = sqrtf(zv[0] * zv[0] + zv[1] * zv[1] + zv[2] * zv[2] + EPSq);
        const float zsc = (1.0f / (1.0f + __expf(-zn))) / zn;
        const float zv0 = zv[0] * zsc, zv1 = zv[1] * zsc, zv2 = zv[2] * zsc;
        const float phs = tanhf(ps_in);
        const float pn  = sqrtf(pv[0] * pv[0] + pv[1] * pv[1] + pv[2] * pv[2] + EPSq);
        const float psc = tanhf(pn) / pn;
        const float pv0 = pv[0] * psc, pv1 = pv[1] * psc, pv2 = pv[2] * psc;
        const float gfs = fabsf(zs);
        const float gfv = sqrtf(zv0 * zv0 + zv1 * zv1 + zv2 * zv2 + EPSq);

        float* ob = out + (size_t)n * CHq * Nq + bnode;
        const float sh_s = SH[u15];
        ob[u15 * Nq] = sh_s + gfs * (phs + sh_s);
#pragma unroll
        for (int j = 0; j < 3; ++j) {
            const float shv = SH[16 + u15 * 3 + j];
            const float pvj = (j == 0) ? pv0 : ((j == 1) ? pv1 : pv2);
            ob[(16 + u15 * 3 + j) * Nq] = shv + gfv * (pvj + shv);
        }
    }
}

// ---------------------------------------------------------------------------
extern "C" void kernel_launch(void* const* d_in, const int* in_sizes, int n_in,
                              void* d_out, int out_size, void* d_ws, size_t ws_size,
                              hipStream_t stream) {
    const float* x      = (const float*)d_in[0];
    const float* h_nei  = (const float*)d_in[1];
    const float* hdiff  = (const float*)d_in[2];
    const float* mask   = (const float*)d_in[3];
    const float* w00    = (const float*)d_in[4];
    const float* w10    = (const float*)d_in[5];
    const float* w01    = (const float*)d_in[6];
    const float* w11    = (const float*)d_in[7];
    const float* wz0    = (const float*)d_in[8];
    const float* wz1    = (const float*)d_in[9];
    const float* wr10   = (const float*)d_in[10];
    const float* wr11   = (const float*)d_in[11];
    const float* wr20   = (const float*)d_in[12];
    const float* wr21   = (const float*)d_in[13];
    const float* wp0    = (const float*)d_in[14];
    const float* wp1    = (const float*)d_in[15];
    float* out = (float*)d_out;
    float* pc  = (float*)d_ws;   // 320 * 24 * 16 * 16 B = 1,966,080 bytes

    se3_precomp<<<(Bq * Nq) / 4, 256, 0, stream>>>(
        h_nei, x, w00, w10, w01, w11, wr10, wr11, wr20, wr21, pc);
    se3_main<<<(Bq * Nq) / 2, 256, 0, stream>>>(
        x, hdiff, mask, wz0, wz1, wp0, wp1, pc, out);
}